// Round 1
// baseline (442.426 us; speedup 1.0000x reference)
//
#include <hip/hip_runtime.h>

// Problem constants (fixed by the reference's setup_inputs).
#define BATCH 8
#define CH    16
#define HH    512
#define WW    512
#define HW    (HH * WW)   // 262144

// One thread per (b, h, w). Computes bilinear weights/offsets once, then
// loops the 16 channels: 4 gathers + 1 coalesced store each.
// Validity per reference: tested on UNCLIPPED floor coords; mask is the
// hard-thresholded sum of valid weights, exactly 0 or 1, so folding it into
// the weights is bit-exact vs. the reference's out*mask.
__global__ __launch_bounds__(256) void warp_kernel(
    const float* __restrict__ img,
    const float* __restrict__ flo,
    float* __restrict__ out)
{
    const int idx = blockIdx.x * 256 + threadIdx.x;  // [0, BATCH*HW)
    const int b  = idx >> 18;          // / HW
    const int hw = idx & (HW - 1);
    const int h  = hw >> 9;            // / WW
    const int w  = hw & (WW - 1);

    // Flow: [B, 2, H, W] — coalesced loads.
    const float* fb = flo + b * 2 * HW;
    const float fx = fb[hw];
    const float fy = fb[HW + hw];

    const float gx = (float)w + fx;
    const float gy = (float)h + fy;

    const float x0f = floorf(gx);
    const float y0f = floorf(gy);
    const float wx1 = gx - x0f, wx0 = 1.0f - wx1;
    const float wy1 = gy - y0f, wy0 = 1.0f - wy1;

    // Validity on unclipped coords (float compare, exactly like the ref).
    const float x1f = x0f + 1.0f;
    const float y1f = y0f + 1.0f;
    const bool vx0 = (x0f >= 0.0f) && (x0f <= (float)(WW - 1));
    const bool vx1 = (x1f >= 0.0f) && (x1f <= (float)(WW - 1));
    const bool vy0 = (y0f >= 0.0f) && (y0f <= (float)(HH - 1));
    const bool vy1 = (y1f >= 0.0f) && (y1f <= (float)(HH - 1));

    float w00 = wx0 * wy0 * ((vx0 && vy0) ? 1.0f : 0.0f);
    float w01 = wx1 * wy0 * ((vx1 && vy0) ? 1.0f : 0.0f);
    float w10 = wx0 * wy1 * ((vx0 && vy1) ? 1.0f : 0.0f);
    float w11 = wx1 * wy1 * ((vx1 && vy1) ? 1.0f : 0.0f);

    // mask = grid_sample(ones) thresholded; exactly 0 or 1 -> fold into weights.
    const float msum = w00 + w01 + w10 + w11;
    const float mask = (msum < 0.9999f) ? 0.0f : 1.0f;
    w00 *= mask; w01 *= mask; w10 *= mask; w11 *= mask;

    // Clipped integer indices (always in-bounds -> unconditional loads OK;
    // invalid corners have weight exactly 0).
    const int x0 = min(max((int)x0f, 0), WW - 1);
    const int x1 = min(max((int)x0f + 1, 0), WW - 1);
    const int y0 = min(max((int)y0f, 0), HH - 1);
    const int y1 = min(max((int)y0f + 1, 0), HH - 1);

    const int o00 = y0 * WW + x0;
    const int o01 = y0 * WW + x1;
    const int o10 = y1 * WW + x0;
    const int o11 = y1 * WW + x1;

    const float* ib = img + (size_t)b * CH * HW;
    float*       ob = out + (size_t)b * CH * HW + hw;

#pragma unroll
    for (int c = 0; c < CH; ++c) {
        const float* p = ib + c * HW;
        const float v = p[o00] * w00 + p[o01] * w01
                      + p[o10] * w10 + p[o11] * w11;
        ob[c * HW] = v;
    }
}

extern "C" void kernel_launch(void* const* d_in, const int* in_sizes, int n_in,
                              void* d_out, int out_size, void* d_ws, size_t ws_size,
                              hipStream_t stream) {
    const float* img = (const float*)d_in[0];  // [8,16,512,512] fp32
    const float* flo = (const float*)d_in[1];  // [8,2,512,512] fp32
    float* out = (float*)d_out;                // [8,16,512,512] fp32

    const int total  = BATCH * HW;             // 2,097,152 threads
    const int blocks = total / 256;            // 8192
    warp_kernel<<<blocks, 256, 0, stream>>>(img, flo, out);
}

// Round 2
// 417.387 us; speedup vs baseline: 1.0600x; 1.0600x over previous
//
#include <hip/hip_runtime.h>

// Problem constants (fixed by the reference's setup_inputs).
#define BATCH 8
#define CH    16
#define HH    512
#define WW    512
#define HW    (HH * WW)     // 262144

#define TILE  32            // output tile edge per block
#define RPAD  16            // halo radius staged in LDS (covers |flow| < ~2sigma..6sigma)
#define REG   64            // staged region edge = TILE + 2*RPAD
#define RSTR  68            // LDS row stride (floats): 16B-aligned rows, 4-bank row skew
#define NPX   4             // pixels per thread = TILE*TILE / 256

// One block = one (b, 32x32 tile), all 16 channels sequentially.
// Per channel: coalesced-stage 64x64 region into LDS, then bilinear-gather
// from LDS. ~2% of pixels have a corner outside the halo -> predicated
// global-gather fallback (identical math).
// Validity per reference: tested on UNCLIPPED floor coords; mask (0/1) folded
// into the weights; clamped indices are always in-bounds so loads are
// unconditional and weight=0 kills invalid corners.
__global__ __launch_bounds__(256) void warp_tiled(
    const float* __restrict__ img,
    const float* __restrict__ flo,
    float* __restrict__ out)
{
    __shared__ float sreg[REG * RSTR];   // 64*68*4 = 17408 B

    const int t    = threadIdx.x;
    const int tile = blockIdx.x;          // 0..2047
    const int b    = tile >> 8;
    const int ty   = (tile >> 4) & 15;
    const int tx   = tile & 15;
    const int xb   = tx * TILE;
    const int yb   = ty * TILE;
    const int x0r  = xb - RPAD;           // region origin (may be negative)
    const int y0r  = yb - RPAD;

    // ---- per-pixel precompute (reused across all 16 channels) ----
    float w00[NPX], w01[NPX], w10[NPX], w11[NPX];
    int   l00[NPX], g00[NPX], dxv[NPX], dyv[NPX], obase[NPX];
    bool  inreg[NPX];

    const float* fb = flo + (size_t)b * 2 * HW;

#pragma unroll
    for (int p = 0; p < NPX; ++p) {
        const int pix = p * 256 + t;      // 0..1023 within tile
        const int row = pix >> 5;         // 0..31
        const int col = pix & 31;
        const int h   = yb + row;
        const int w   = xb + col;
        const int hw  = h * WW + w;

        const float fx = fb[hw];          // coalesced
        const float fy = fb[HW + hw];
        const float gx = (float)w + fx;
        const float gy = (float)h + fy;

        const float x0f = floorf(gx), y0f = floorf(gy);
        const float wx1 = gx - x0f, wx0 = 1.0f - wx1;
        const float wy1 = gy - y0f, wy0 = 1.0f - wy1;

        const bool vx0 = (x0f >= 0.0f)        && (x0f <= (float)(WW - 1));
        const bool vx1 = (x0f + 1.0f >= 0.0f) && (x0f + 1.0f <= (float)(WW - 1));
        const bool vy0 = (y0f >= 0.0f)        && (y0f <= (float)(HH - 1));
        const bool vy1 = (y0f + 1.0f >= 0.0f) && (y0f + 1.0f <= (float)(HH - 1));

        float a00 = wx0 * wy0 * ((vx0 && vy0) ? 1.0f : 0.0f);
        float a01 = wx1 * wy0 * ((vx1 && vy0) ? 1.0f : 0.0f);
        float a10 = wx0 * wy1 * ((vx0 && vy1) ? 1.0f : 0.0f);
        float a11 = wx1 * wy1 * ((vx1 && vy1) ? 1.0f : 0.0f);

        const float msum = a00 + a01 + a10 + a11;
        const float mask = (msum < 0.9999f) ? 0.0f : 1.0f;
        w00[p] = a00 * mask; w01[p] = a01 * mask;
        w10[p] = a10 * mask; w11[p] = a11 * mask;

        const int x0 = min(max((int)x0f, 0), WW - 1);
        const int x1 = min(max((int)x0f + 1, 0), WW - 1);
        const int y0 = min(max((int)y0f, 0), HH - 1);
        const int y1 = min(max((int)y0f + 1, 0), HH - 1);

        dxv[p] = x1 - x0;                 // 0 or 1
        dyv[p] = y1 - y0;
        g00[p] = y0 * WW + x0;
        l00[p] = (y0 - y0r) * RSTR + (x0 - x0r);
        inreg[p] = (x0 >= x0r) && (x1 <= x0r + REG - 1) &&
                   (y0 >= y0r) && (y1 <= y0r + REG - 1);
        obase[p] = hw;
    }

    // ---- staging geometry (per thread, channel-invariant) ----
    const int lane  = t & 63;             // region column within row
    const int wv    = t >> 6;             // wave id 0..3
    const int gxcol = min(max(x0r + lane, 0), WW - 1);   // clamped global col
    const size_t ibase = (size_t)b * CH * HW;

    for (int c = 0; c < CH; ++c) {
        const float* ic = img + ibase + (size_t)c * HW;

        // stage 64x64 region: wave loads one contiguous 64-float row slice
#pragma unroll
        for (int k = 0; k < 16; ++k) {
            const int ry = k * 4 + wv;                       // 0..63
            const int gy = min(max(y0r + ry, 0), HH - 1);    // clamped row
            sreg[ry * RSTR + lane] = ic[gy * WW + gxcol];
        }
        __syncthreads();

        float* oc = out + ibase + (size_t)c * HW;
#pragma unroll
        for (int p = 0; p < NPX; ++p) {
            float v;
            if (inreg[p]) {
                const int l = l00[p];
                v = w00[p] * sreg[l]
                  + w01[p] * sreg[l + dxv[p]]
                  + w10[p] * sreg[l + RSTR * dyv[p]]
                  + w11[p] * sreg[l + dxv[p] + RSTR * dyv[p]];
            } else {
                const int g = g00[p];
                v = w00[p] * ic[g]
                  + w01[p] * ic[g + dxv[p]]
                  + w10[p] * ic[g + WW * dyv[p]]
                  + w11[p] * ic[g + dxv[p] + WW * dyv[p]];
            }
            oc[obase[p]] = v;             // coalesced (two 128B segs/wave)
        }
        __syncthreads();                  // protect sreg before next channel
    }
}

extern "C" void kernel_launch(void* const* d_in, const int* in_sizes, int n_in,
                              void* d_out, int out_size, void* d_ws, size_t ws_size,
                              hipStream_t stream) {
    const float* img = (const float*)d_in[0];  // [8,16,512,512] fp32
    const float* flo = (const float*)d_in[1];  // [8,2,512,512] fp32
    float* out = (float*)d_out;                // [8,16,512,512] fp32

    const int blocks = BATCH * (HH / TILE) * (WW / TILE);  // 8*16*16 = 2048
    warp_tiled<<<blocks, 256, 0, stream>>>(img, flo, out);
}

// Round 3
// 374.261 us; speedup vs baseline: 1.1821x; 1.1152x over previous
//
#include <hip/hip_runtime.h>

// Problem constants (fixed by the reference's setup_inputs).
#define BATCH 8
#define CH    16
#define HH    512
#define WW    512
#define HW    (HH * WW)     // 262144

#define TILE  32            // output tile edge per block
#define RPAD  16            // halo radius staged in LDS
#define REG   64            // staged region edge = TILE + 2*RPAD
#define NPX   4             // pixels per thread = TILE*TILE / 256
#define CG    4             // channels per group (float4 channel-last in LDS)
#define NG    (CH / CG)     // 4 groups

// One block = one (b, 32x32 tile). Channel-last LDS: sreg[y*REG+x] holds the
// float4 of 4 consecutive channels at (y,x). Staging: 4 coalesced global
// loads + 1 conflict-free ds_write_b128 per 64-wide row slice. Gather: 4
// ds_read_b128 per pixel per group (minimum bytes, no per-channel rescans).
// LDS gather addresses are CLAMPED into the region (branchless); the ~2.4%
// of pixels whose corners fall outside the staged halo get finite garbage,
// then are overwritten by a per-pixel global-gather fixup loop afterwards
// (same thread stores both -> program order guarantees the final value).
// Validity per reference: tested on UNCLIPPED floor coords; the 0/1 mask is
// folded into the weights (bit-exact); clamped image indices are always
// in-bounds so fixup loads are unconditional.
__global__ __launch_bounds__(256) void warp_c4(
    const float* __restrict__ img,
    const float* __restrict__ flo,
    float* __restrict__ out)
{
    __shared__ float4 sreg[REG * REG];   // 64 KB

    const int t    = threadIdx.x;
    const int tile = blockIdx.x;          // 0..2047
    const int b    = tile >> 8;
    const int ty   = (tile >> 4) & 15;
    const int tx   = tile & 15;
    const int xb   = tx * TILE;
    const int yb   = ty * TILE;
    const int x0r  = xb - RPAD;           // region origin (may be negative)
    const int y0r  = yb - RPAD;

    // ---- per-pixel precompute (channel-invariant) ----
    float w00[NPX], w01[NPX], w10[NPX], w11[NPX];
    int   lidx[NPX], g00[NPX], dxv[NPX], dyv[NPX], obase[NPX];
    bool  fb[NPX];

    const float* fbp = flo + (size_t)b * 2 * HW;

#pragma unroll
    for (int p = 0; p < NPX; ++p) {
        const int pix = p * 256 + t;      // 0..1023 within tile
        const int row = pix >> 5;
        const int col = pix & 31;
        const int h   = yb + row;
        const int w   = xb + col;
        const int hw  = h * WW + w;

        const float fx = fbp[hw];         // coalesced
        const float fy = fbp[HW + hw];
        const float gx = (float)w + fx;
        const float gy = (float)h + fy;

        const float x0f = floorf(gx), y0f = floorf(gy);
        const float wx1 = gx - x0f, wx0 = 1.0f - wx1;
        const float wy1 = gy - y0f, wy0 = 1.0f - wy1;

        const bool vx0 = (x0f >= 0.0f)        && (x0f <= (float)(WW - 1));
        const bool vx1 = (x0f + 1.0f >= 0.0f) && (x0f + 1.0f <= (float)(WW - 1));
        const bool vy0 = (y0f >= 0.0f)        && (y0f <= (float)(HH - 1));
        const bool vy1 = (y0f + 1.0f >= 0.0f) && (y0f + 1.0f <= (float)(HH - 1));

        float a00 = wx0 * wy0 * ((vx0 && vy0) ? 1.0f : 0.0f);
        float a01 = wx1 * wy0 * ((vx1 && vy0) ? 1.0f : 0.0f);
        float a10 = wx0 * wy1 * ((vx0 && vy1) ? 1.0f : 0.0f);
        float a11 = wx1 * wy1 * ((vx1 && vy1) ? 1.0f : 0.0f);

        const float msum = a00 + a01 + a10 + a11;
        const float mask = (msum < 0.9999f) ? 0.0f : 1.0f;
        w00[p] = a00 * mask; w01[p] = a01 * mask;
        w10[p] = a10 * mask; w11[p] = a11 * mask;

        const int x0 = min(max((int)x0f, 0), WW - 1);
        const int x1 = min(max((int)x0f + 1, 0), WW - 1);
        const int y0 = min(max((int)y0f, 0), HH - 1);
        const int y1 = min(max((int)y0f + 1, 0), HH - 1);

        const int dx = x1 - x0;           // 0 or 1
        const int dy = y1 - y0;
        dxv[p] = dx; dyv[p] = dy;
        g00[p] = y0 * WW + x0;
        obase[p] = hw;

        const int xl = x0 - x0r;          // region-local (may be out of range)
        const int yl = y0 - y0r;
        fb[p] = !((xl >= 0) && (xl + dx <= REG - 1) &&
                  (yl >= 0) && (yl + dy <= REG - 1));
        // Clamp to [0, REG-2]: exact for every in-region pixel (an in-region
        // corner with xl==REG-1 implies dx==0 is impossible here -- proven by
        // tile geometry), safe-finite for fallback pixels.
        lidx[p] = min(max(yl, 0), REG - 2) * REG + min(max(xl, 0), REG - 2);
    }

    // ---- staging geometry (channel-invariant) ----
    const int lane = t & 63;
    const int wv   = t >> 6;
    const int gxc  = min(max(x0r + lane, 0), WW - 1);
    const size_t ib = (size_t)b * CH * HW;

    for (int g = 0; g < NG; ++g) {
        const float* c0 = img + ib + (size_t)(g * CG) * HW;

        // stage 64x64 region, 4 channels deep (channel-last float4)
#pragma unroll
        for (int k = 0; k < 16; ++k) {
            const int ry = k * 4 + wv;                       // 0..63
            const int gy = min(max(y0r + ry, 0), HH - 1);
            const int go = gy * WW + gxc;
            float4 v;
            v.x = c0[go];
            v.y = c0[go + HW];
            v.z = c0[go + 2 * HW];
            v.w = c0[go + 3 * HW];
            sreg[ry * REG + lane] = v;    // ds_write_b128, conflict-free
        }
        __syncthreads();

        float* o0 = out + ib + (size_t)(g * CG) * HW;
#pragma unroll
        for (int p = 0; p < NPX; ++p) {
            const int l   = lidx[p];
            const int dx  = dxv[p];
            const int dyo = dyv[p] * REG;
            const float4 v00 = sreg[l];
            const float4 v01 = sreg[l + dx];
            const float4 v10 = sreg[l + dyo];
            const float4 v11 = sreg[l + dx + dyo];
            float4 r;
            r.x = w00[p]*v00.x + w01[p]*v01.x + w10[p]*v10.x + w11[p]*v11.x;
            r.y = w00[p]*v00.y + w01[p]*v01.y + w10[p]*v10.y + w11[p]*v11.y;
            r.z = w00[p]*v00.z + w01[p]*v01.z + w10[p]*v10.z + w11[p]*v11.z;
            r.w = w00[p]*v00.w + w01[p]*v01.w + w10[p]*v10.w + w11[p]*v11.w;
            const int ob = obase[p];
            o0[ob]          = r.x;        // coalesced per channel
            o0[ob + HW]     = r.y;
            o0[ob + 2*HW]   = r.z;
            o0[ob + 3*HW]   = r.w;
        }
        __syncthreads();                  // protect sreg before next group
    }

    // ---- fixup: redo fallback pixels from global (all 16 channels) ----
#pragma unroll
    for (int p = 0; p < NPX; ++p) {
        if (fb[p]) {
            const int gA  = g00[p];
            const int dx  = dxv[p];
            const int dyo = dyv[p] * WW;
            const float a = w00[p], bw = w01[p], cw = w10[p], dw = w11[p];
            const float* ic = img + ib;
            float*       oc = out + ib + obase[p];
            for (int c = 0; c < CH; ++c) {
                const float* pc = ic + (size_t)c * HW;
                const float v = a  * pc[gA]
                              + bw * pc[gA + dx]
                              + cw * pc[gA + dyo]
                              + dw * pc[gA + dx + dyo];
                oc[(size_t)c * HW] = v;
            }
        }
    }
}

extern "C" void kernel_launch(void* const* d_in, const int* in_sizes, int n_in,
                              void* d_out, int out_size, void* d_ws, size_t ws_size,
                              hipStream_t stream) {
    const float* img = (const float*)d_in[0];  // [8,16,512,512] fp32
    const float* flo = (const float*)d_in[1];  // [8,2,512,512] fp32
    float* out = (float*)d_out;                // [8,16,512,512] fp32

    const int blocks = BATCH * (HH / TILE) * (WW / TILE);  // 2048
    warp_c4<<<blocks, 256, 0, stream>>>(img, flo, out);
}